// Round 5
// baseline (1143.090 us; speedup 1.0000x reference)
//
#include <hip/hip_runtime.h>
#include <math.h>

// Problem constants (reference: S,B,I,H = 1024,512,5,32; G=4H=128)
#define S_LEN 1024
#define BATCH 512
#define HID   32

__device__ __forceinline__ float fast_rcp(float x) { return __builtin_amdgcn_rcpf(x); }

__device__ __forceinline__ float sigmoid_f(float x) {
    return fast_rcp(1.0f + __expf(-x));
}

__device__ __forceinline__ float tanh_f(float x) {
    // overflow-safe: t = e^{-2|x|} in (0,1]; tanh = sign(x)*(1-t)/(1+t)
    float t = __expf(-2.0f * fabsf(x));
    float r = (1.0f - t) * fast_rcp(1.0f + t);
    return copysignf(r, x);
}

// broadcast lane k's float to all lanes through an SGPR (VALU only, no LDS)
__device__ __forceinline__ float rl(float v, int k) {
    return __int_as_float(__builtin_amdgcn_readlane(__float_as_int(v), k));
}

// Fused 3-layer LSTM + collapsed linear head, software-pipelined across waves.
// Block = 192 threads = 3 waves; wave w = layer w; blockIdx = batch element.
// At tick t, wave w processes step s = t - w; ONE __syncthreads per tick.
// Round-5 changes vs round 4:
//  (a) x staged into LDS once -> no global loads inside the tick loop, so the
//      implicit vmcnt(0) drain at __syncthreads costs nothing.
//  (b) Whh.h partial for the NEXT step is computed pre-barrier (right after
//      h_new) and carried across the barrier in 8 accumulator VGPRs, so the
//      post-barrier critical chain is only: input read -> input FMAs ->
//      nonlinearity -> ring write.
// Head: y = relu((w3 W2 W1) . h2 + (w3 W2 b1 + w3 b2 + b3)) computed in wave 2.
// Lane l owns gates l and l+64 of its layer (order i,f,g,o).
__global__ __launch_bounds__(192, 2)
void lstm3_head(const float* __restrict__ x,
                const float* __restrict__ Wih0, const float* __restrict__ Whh0,
                const float* __restrict__ bih0, const float* __restrict__ bhh0,
                const float* __restrict__ Wih1, const float* __restrict__ Whh1,
                const float* __restrict__ bih1, const float* __restrict__ bhh1,
                const float* __restrict__ Wih2, const float* __restrict__ Whh2,
                const float* __restrict__ bih2, const float* __restrict__ bhh2,
                const float* __restrict__ w1, const float* __restrict__ b1,
                const float* __restrict__ w2, const float* __restrict__ b2,
                const float* __restrict__ w3, const float* __restrict__ b3,
                float* __restrict__ out)
{
    const int b = blockIdx.x;
    const int w = threadIdx.x >> 6;   // wave id == layer id, 0..2
    const int l = threadIdx.x & 63;
    const int j = l & 31;
    const bool lowHalf = (l < 32);
    const int gA = l;
    const int gB = l + 64;

    __shared__ float xlds[S_LEN * 5];     // x[s][0..4] for this batch element
    __shared__ float ring[2][2][HID];     // [parity][producer layer][unit]

    // ---- one-time x staging (global -> LDS) ----
    {
        const float* xb = x + (size_t)b * 5;
        for (int i = threadIdx.x; i < S_LEN * 5; i += 192) {
            int s = i / 5;
            int k = i - 5 * s;
            xlds[i] = xb[(size_t)s * (BATCH * 5) + k];
        }
    }
    for (int i = threadIdx.x; i < 2 * 2 * HID; i += 192)
        (&ring[0][0][0])[i] = 0.0f;

    const float* Wih = (w == 0) ? Wih0 : (w == 1) ? Wih1 : Wih2;
    const float* Whh = (w == 0) ? Whh0 : (w == 1) ? Whh1 : Whh2;
    const float* bih = (w == 0) ? bih0 : (w == 1) ? bih1 : bih2;
    const float* bhh = (w == 0) ? bhh0 : (w == 1) ? bhh1 : bhh2;

    float whhA[HID], whhB[HID];
#pragma unroll
    for (int k = 0; k < HID; ++k) {
        whhA[k] = Whh[gA * HID + k];
        whhB[k] = Whh[gB * HID + k];
    }
    float wihA[HID], wihB[HID];
    if (w == 0) {
#pragma unroll
        for (int k = 0; k < 5; ++k) {
            wihA[k] = Wih[gA * 5 + k];
            wihB[k] = Wih[gB * 5 + k];
        }
    } else {
#pragma unroll
        for (int k = 0; k < HID; ++k) {
            wihA[k] = Wih[gA * HID + k];
            wihB[k] = Wih[gB * HID + k];
        }
    }
    const float biasA = bih[gA] + bhh[gA];
    const float biasB = bih[gB] + bhh[gB];

    // ---- wave-2 prologue: collapse the linear MLP head ----
    float u_own = 0.0f, beta = 0.0f;
    if (w == 2) {
        float t_own = 0.0f;
#pragma unroll
        for (int k = 0; k < HID; ++k)
            t_own += w3[k] * w2[k * HID + j];
        float uo = 0.0f, bt = 0.0f;
#pragma unroll
        for (int k = 0; k < HID; ++k) {
            float tk = rl(t_own, k);       // t_k lives in lane k
            uo += tk * w1[k * HID + j];
            bt += tk * b1[k] + w3[k] * b2[k];
        }
        u_own = uo;
        beta = bt + b3[0];
    }

    float c = 0.0f;
    float h = 0.0f;   // h_{l&31} of this layer (redundant in both halves)

    // Carried Whh.h partial for the upcoming step (h = 0 initially)
    float aA0 = biasA, aA1 = 0.f, aA2 = 0.f, aA3 = 0.f;
    float aB0 = biasB, aB1 = 0.f, aB2 = 0.f, aB3 = 0.f;

    __syncthreads();  // staging + ring init visible

    for (int t = 0; t < S_LEN + 2; ++t) {
        const int s = t - w;
        const bool active = ((unsigned)s < S_LEN);
        const int p = t & 1;

        // ---- post-barrier phase: input contribution only ----
        float iA0 = 0.f, iA1 = 0.f, iA2 = 0.f, iA3 = 0.f;
        float iB0 = 0.f, iB1 = 0.f, iB2 = 0.f, iB3 = 0.f;

        if (w == 0) {
            if (active) {
                const float* xs = &xlds[s * 5];
                float x0 = xs[0], x1 = xs[1], x2 = xs[2], x3 = xs[3], x4 = xs[4];
                iA0 = wihA[0] * x0 + wihA[4] * x4;
                iB0 = wihB[0] * x0 + wihB[4] * x4;
                iA1 = wihA[1] * x1;  iB1 = wihB[1] * x1;
                iA2 = wihA[2] * x2;  iB2 = wihB[2] * x2;
                iA3 = wihA[3] * x3;  iB3 = wihB[3] * x3;
            }
        } else {
            const float4* r4 = reinterpret_cast<const float4*>(&ring[p][w - 1][0]);
#pragma unroll
            for (int k4 = 0; k4 < HID / 4; ++k4) {
                float4 hv = r4[k4];
                iA0 += wihA[4 * k4 + 0] * hv.x;  iB0 += wihB[4 * k4 + 0] * hv.x;
                iA1 += wihA[4 * k4 + 1] * hv.y;  iB1 += wihB[4 * k4 + 1] * hv.y;
                iA2 += wihA[4 * k4 + 2] * hv.z;  iB2 += wihB[4 * k4 + 2] * hv.z;
                iA3 += wihA[4 * k4 + 3] * hv.w;  iB3 += wihB[4 * k4 + 3] * hv.w;
            }
        }
        float accA = ((aA0 + iA0) + (aA1 + iA1)) + ((aA2 + iA2) + (aA3 + iA3));
        float accB = ((aB0 + iB0) + (aB1 + iB1)) + ((aB2 + iB2) + (aB3 + iB3));

        // ---- exchange halves: both halves get all 4 gates of unit j ----
        float pA = __shfl_xor(accA, 32);
        float pB = __shfl_xor(accB, 32);
        float gi = lowHalf ? accA : pA;
        float gf = lowHalf ? pA : accA;
        float gg = lowHalf ? accB : pB;
        float go = lowHalf ? pB : accB;

        gi = sigmoid_f(gi);
        gf = sigmoid_f(gf);
        gg = tanh_f(gg);
        go = sigmoid_f(go);
        float c_new = gf * c + gi * gg;
        float h_new = go * tanh_f(c_new);   // redundant in both halves

        if (active) {
            c = c_new;
            h = h_new;
            if (w < 2) {
                if (lowHalf) ring[p ^ 1][w][j] = h_new;   // next tick's input for wave w+1
            } else {
                // fused head: y[s,b] = relu(u . h + beta), butterfly over 32 units
                float prt = u_own * h_new;
                prt += __shfl_xor(prt, 1);
                prt += __shfl_xor(prt, 2);
                prt += __shfl_xor(prt, 4);
                prt += __shfl_xor(prt, 8);
                prt += __shfl_xor(prt, 16);
                if (l == 0) out[(size_t)s * BATCH + b] = fmaxf(prt + beta, 0.0f);
            }
        }

        // ---- pre-barrier phase: Whh . h partial for the NEXT step ----
        aA0 = biasA; aA1 = 0.f; aA2 = 0.f; aA3 = 0.f;
        aB0 = biasB; aB1 = 0.f; aB2 = 0.f; aB3 = 0.f;
#pragma unroll
        for (int k = 0; k < HID; k += 4) {
            float h0 = rl(h, k + 0);
            float h1 = rl(h, k + 1);
            float h2 = rl(h, k + 2);
            float h3 = rl(h, k + 3);
            aA0 += whhA[k + 0] * h0;  aB0 += whhB[k + 0] * h0;
            aA1 += whhA[k + 1] * h1;  aB1 += whhB[k + 1] * h1;
            aA2 += whhA[k + 2] * h2;  aB2 += whhB[k + 2] * h2;
            aA3 += whhA[k + 3] * h3;  aB3 += whhB[k + 3] * h3;
        }

        __syncthreads();  // tick boundary (no outstanding global loads to drain)
    }
}

extern "C" void kernel_launch(void* const* d_in, const int* in_sizes, int n_in,
                              void* d_out, int out_size, void* d_ws, size_t ws_size,
                              hipStream_t stream)
{
    const float* x    = (const float*)d_in[0];
    const float* Wih0 = (const float*)d_in[1];
    const float* Whh0 = (const float*)d_in[2];
    const float* bih0 = (const float*)d_in[3];
    const float* bhh0 = (const float*)d_in[4];
    const float* Wih1 = (const float*)d_in[5];
    const float* Whh1 = (const float*)d_in[6];
    const float* bih1 = (const float*)d_in[7];
    const float* bhh1 = (const float*)d_in[8];
    const float* Wih2 = (const float*)d_in[9];
    const float* Whh2 = (const float*)d_in[10];
    const float* bih2 = (const float*)d_in[11];
    const float* bhh2 = (const float*)d_in[12];
    const float* w1   = (const float*)d_in[13];
    const float* b1   = (const float*)d_in[14];
    const float* w2   = (const float*)d_in[15];
    const float* b2   = (const float*)d_in[16];
    const float* w3   = (const float*)d_in[17];
    const float* b3   = (const float*)d_in[18];

    lstm3_head<<<BATCH, 192, 0, stream>>>(x, Wih0, Whh0, bih0, bhh0,
                                          Wih1, Whh1, bih1, bhh1,
                                          Wih2, Whh2, bih2, bhh2,
                                          w1, b1, w2, b2, w3, b3,
                                          (float*)d_out);
}

// Round 6
// 994.420 us; speedup vs baseline: 1.1495x; 1.1495x over previous
//
#include <hip/hip_runtime.h>
#include <math.h>

// Problem constants (reference: S,B,I,H = 1024,512,5,32; G=4H=128)
#define S_LEN  1024
#define BATCH  512
#define HID    32
#define RING_D 8   // ring depth (steps of producer/consumer slack)

__device__ __forceinline__ float fast_rcp(float x) { return __builtin_amdgcn_rcpf(x); }

__device__ __forceinline__ float sigmoid_f(float x) {
    return fast_rcp(1.0f + __expf(-x));
}

__device__ __forceinline__ float tanh_f(float x) {
    // overflow-safe: t = e^{-2|x|} in (0,1]; tanh = sign(x)*(1-t)/(1+t)
    float t = __expf(-2.0f * fabsf(x));
    float r = (1.0f - t) * fast_rcp(1.0f + t);
    return copysignf(r, x);
}

// broadcast lane k's float to all lanes through an SGPR (VALU only, no LDS)
__device__ __forceinline__ float rl(float v, int k) {
    return __int_as_float(__builtin_amdgcn_readlane(__float_as_int(v), k));
}

// Fused 3-layer LSTM + collapsed linear head, DECOUPLED waves (no per-step
// __syncthreads). Block = 192 threads = 3 waves; wave w = layer w; blockIdx =
// batch element. Layer handoff: 8-deep LDS ring + per-slot sequence flag
// (producer: release-store flag after data; consumer: acquire-spin on flag).
// Progress counters stop the producer from lapping the consumer. Waves drift
// up to RING_D steps, so the 3-way rendezvous cost and cross-wave jitter
// coupling of the barrier version are gone.
// Whh.h runs at step START against the carried register h (off the handoff
// critical path — the R5 lesson in reverse).
// Head: y = relu((w3 W2 W1) . h2 + (w3 W2 b1 + w3 b2 + b3)) folded into wave 2.
// Lane l owns gates l and l+64 of its layer (order i,f,g,o).
__global__ __launch_bounds__(192)
void lstm3_async(const float* __restrict__ x,
                 const float* __restrict__ Wih0, const float* __restrict__ Whh0,
                 const float* __restrict__ bih0, const float* __restrict__ bhh0,
                 const float* __restrict__ Wih1, const float* __restrict__ Whh1,
                 const float* __restrict__ bih1, const float* __restrict__ bhh1,
                 const float* __restrict__ Wih2, const float* __restrict__ Whh2,
                 const float* __restrict__ bih2, const float* __restrict__ bhh2,
                 const float* __restrict__ w1, const float* __restrict__ b1,
                 const float* __restrict__ w2, const float* __restrict__ b2,
                 const float* __restrict__ w3, const float* __restrict__ b3,
                 float* __restrict__ out)
{
    const int b = blockIdx.x;
    const int w = threadIdx.x >> 6;   // wave id == layer id, 0..2
    const int l = threadIdx.x & 63;
    const int j = l & 31;
    const bool lowHalf = (l < 32);
    const int gA = l;
    const int gB = l + 64;

    __shared__ float xlds[S_LEN * 5];          // x[s][k] for this batch element
    __shared__ float ring[2][RING_D][HID];     // [producer layer][slot][unit]
    __shared__ int   flg[2][RING_D];           // == s+1 when slot holds step s
    __shared__ int   prog[2];                  // consumer: steps completed

    // ---- one-time staging + sync-state init ----
    {
        const float* xb = x + (size_t)b * 5;
        for (int i = threadIdx.x; i < S_LEN * 5; i += 192) {
            int s = i / 5;
            int k = i - 5 * s;
            xlds[i] = xb[(size_t)s * (BATCH * 5) + k];
        }
    }
    if (threadIdx.x < 2 * RING_D) (&flg[0][0])[threadIdx.x] = 0;
    if (threadIdx.x < 2) prog[threadIdx.x] = 0;
    __syncthreads();   // the ONLY barrier

    const float* Wih = (w == 0) ? Wih0 : (w == 1) ? Wih1 : Wih2;
    const float* Whh = (w == 0) ? Whh0 : (w == 1) ? Whh1 : Whh2;
    const float* bih = (w == 0) ? bih0 : (w == 1) ? bih1 : bih2;
    const float* bhh = (w == 0) ? bhh0 : (w == 1) ? bhh1 : bhh2;

    float whhA[HID], whhB[HID];
#pragma unroll
    for (int k = 0; k < HID; ++k) {
        whhA[k] = Whh[gA * HID + k];
        whhB[k] = Whh[gB * HID + k];
    }
    float wihA[HID], wihB[HID];
    if (w == 0) {
#pragma unroll
        for (int k = 0; k < 5; ++k) {
            wihA[k] = Wih[gA * 5 + k];
            wihB[k] = Wih[gB * 5 + k];
        }
    } else {
#pragma unroll
        for (int k = 0; k < HID; ++k) {
            wihA[k] = Wih[gA * HID + k];
            wihB[k] = Wih[gB * HID + k];
        }
    }
    const float biasA = bih[gA] + bhh[gA];
    const float biasB = bih[gB] + bhh[gB];

    // ---- wave-2 prologue: collapse the linear MLP head ----
    float u_own = 0.0f, beta = 0.0f;
    if (w == 2) {
        float t_own = 0.0f;
#pragma unroll
        for (int k = 0; k < HID; ++k)
            t_own += w3[k] * w2[k * HID + j];
        float uo = 0.0f, bt = 0.0f;
#pragma unroll
        for (int k = 0; k < HID; ++k) {
            float tk = rl(t_own, k);       // t_k lives in lane k
            uo += tk * w1[k * HID + j];
            bt += tk * b1[k] + w3[k] * b2[k];
        }
        u_own = uo;
        beta = bt + b3[0];
    }

    float c = 0.0f;
    float h = 0.0f;   // h_{j} of this layer (redundant in both halves)

    for (int s = 0; s < S_LEN; ++s) {
        const int slot = s & (RING_D - 1);

        // ---- phase A (off handoff path): Whh . h_prev via readlane ----
        float aA0 = biasA, aA1 = 0.f, aA2 = 0.f, aA3 = 0.f;
        float aB0 = biasB, aB1 = 0.f, aB2 = 0.f, aB3 = 0.f;
#pragma unroll
        for (int k = 0; k < HID; k += 4) {
            float h0 = rl(h, k + 0);
            float h1 = rl(h, k + 1);
            float h2 = rl(h, k + 2);
            float h3 = rl(h, k + 3);
            aA0 += whhA[k + 0] * h0;  aB0 += whhB[k + 0] * h0;
            aA1 += whhA[k + 1] * h1;  aB1 += whhB[k + 1] * h1;
            aA2 += whhA[k + 2] * h2;  aB2 += whhB[k + 2] * h2;
            aA3 += whhA[k + 3] * h3;  aB3 += whhB[k + 3] * h3;
        }

        // ---- phase B: input contribution ----
        if (w == 0) {
            const float* xs = &xlds[s * 5];
            float x0 = xs[0], x1 = xs[1], x2 = xs[2], x3 = xs[3], x4 = xs[4];
            aA0 += wihA[0] * x0 + wihA[4] * x4;
            aB0 += wihB[0] * x0 + wihB[4] * x4;
            aA1 += wihA[1] * x1;  aB1 += wihB[1] * x1;
            aA2 += wihA[2] * x2;  aB2 += wihB[2] * x2;
            aA3 += wihA[3] * x3;  aB3 += wihB[3] * x3;
        } else {
            // wait for producer (usually already set: producer runs ahead)
            while (__hip_atomic_load(&flg[w - 1][slot], __ATOMIC_ACQUIRE,
                                     __HIP_MEMORY_SCOPE_WORKGROUP) != s + 1) {}
            const float4* r4 = reinterpret_cast<const float4*>(&ring[w - 1][slot][0]);
#pragma unroll
            for (int k4 = 0; k4 < HID / 4; ++k4) {
                float4 hv = r4[k4];
                aA0 += wihA[4 * k4 + 0] * hv.x;  aB0 += wihB[4 * k4 + 0] * hv.x;
                aA1 += wihA[4 * k4 + 1] * hv.y;  aB1 += wihB[4 * k4 + 1] * hv.y;
                aA2 += wihA[4 * k4 + 2] * hv.z;  aB2 += wihB[4 * k4 + 2] * hv.z;
                aA3 += wihA[4 * k4 + 3] * hv.w;  aB3 += wihB[4 * k4 + 3] * hv.w;
            }
            // free the slot for the producer (release orders the reads above)
            if (l == 0)
                __hip_atomic_store(&prog[w - 1], s + 1, __ATOMIC_RELEASE,
                                   __HIP_MEMORY_SCOPE_WORKGROUP);
        }
        float accA = (aA0 + aA1) + (aA2 + aA3);
        float accB = (aB0 + aB1) + (aB2 + aB3);

        // ---- exchange halves: both halves get all 4 gates of unit j ----
        float pA = __shfl_xor(accA, 32);
        float pB = __shfl_xor(accB, 32);
        float gi = lowHalf ? accA : pA;
        float gf = lowHalf ? pA : accA;
        float gg = lowHalf ? accB : pB;
        float go = lowHalf ? pB : accB;

        gi = sigmoid_f(gi);
        gf = sigmoid_f(gf);
        gg = tanh_f(gg);
        go = sigmoid_f(go);
        c = gf * c + gi * gg;
        h = go * tanh_f(c);   // redundant in both halves

        // ---- handoff / output ----
        if (w < 2) {
            if (s >= RING_D) {
                // don't lap the consumer: need it done with step s-RING_D
                while (__hip_atomic_load(&prog[w], __ATOMIC_ACQUIRE,
                                         __HIP_MEMORY_SCOPE_WORKGROUP)
                       < s - (RING_D - 1)) {}
            }
            if (lowHalf) ring[w][slot][j] = h;
            if (l == 0)
                __hip_atomic_store(&flg[w][slot], s + 1, __ATOMIC_RELEASE,
                                   __HIP_MEMORY_SCOPE_WORKGROUP);
        } else {
            // fused head: y[s,b] = relu(u . h + beta), butterfly over 32 units
            float prt = u_own * h;
            prt += __shfl_xor(prt, 1);
            prt += __shfl_xor(prt, 2);
            prt += __shfl_xor(prt, 4);
            prt += __shfl_xor(prt, 8);
            prt += __shfl_xor(prt, 16);
            if (l == 0) out[(size_t)s * BATCH + b] = fmaxf(prt + beta, 0.0f);
        }
    }
}

extern "C" void kernel_launch(void* const* d_in, const int* in_sizes, int n_in,
                              void* d_out, int out_size, void* d_ws, size_t ws_size,
                              hipStream_t stream)
{
    const float* x    = (const float*)d_in[0];
    const float* Wih0 = (const float*)d_in[1];
    const float* Whh0 = (const float*)d_in[2];
    const float* bih0 = (const float*)d_in[3];
    const float* bhh0 = (const float*)d_in[4];
    const float* Wih1 = (const float*)d_in[5];
    const float* Whh1 = (const float*)d_in[6];
    const float* bih1 = (const float*)d_in[7];
    const float* bhh1 = (const float*)d_in[8];
    const float* Wih2 = (const float*)d_in[9];
    const float* Whh2 = (const float*)d_in[10];
    const float* bih2 = (const float*)d_in[11];
    const float* bhh2 = (const float*)d_in[12];
    const float* w1   = (const float*)d_in[13];
    const float* b1   = (const float*)d_in[14];
    const float* w2   = (const float*)d_in[15];
    const float* b2   = (const float*)d_in[16];
    const float* w3   = (const float*)d_in[17];
    const float* b3   = (const float*)d_in[18];

    lstm3_async<<<BATCH, 192, 0, stream>>>(x, Wih0, Whh0, bih0, bhh0,
                                           Wih1, Whh1, bih1, bhh1,
                                           Wih2, Whh2, bih2, bhh2,
                                           w1, b1, w2, b2, w3, b3,
                                           (float*)d_out);
}